// Round 5
// baseline (393.223 us; speedup 1.0000x reference)
//
#include <hip/hip_runtime.h>
#include <hip/hip_fp16.h>
#include <math.h>

#define BB 256
#define LL 512
#define DD 1024
#define NW 16         // waves per 1024-thread block
#define VROWS 50001   // V+1 rows

// convert 8 halves packed in a float4 into 8 floats at dst[off..off+7]
#define CVT8(dst, off, v) { const __half2* hp2 = (const __half2*)&(v); float2 t; \
    t = __half22float2(hp2[0]); dst[(off)+0] = t.x; dst[(off)+1] = t.y; \
    t = __half22float2(hp2[1]); dst[(off)+2] = t.x; dst[(off)+3] = t.y; \
    t = __half22float2(hp2[2]); dst[(off)+4] = t.x; dst[(off)+5] = t.y; \
    t = __half22float2(hp2[3]); dst[(off)+6] = t.x; dst[(off)+7] = t.y; }

#define CVT8ADD(acc, off, v) { const __half2* hp2 = (const __half2*)&(v); float2 t; \
    t = __half22float2(hp2[0]); acc[(off)+0] += t.x; acc[(off)+1] += t.y; \
    t = __half22float2(hp2[1]); acc[(off)+2] += t.x; acc[(off)+3] += t.y; \
    t = __half22float2(hp2[2]); acc[(off)+4] += t.x; acc[(off)+5] += t.y; \
    t = __half22float2(hp2[3]); acc[(off)+6] += t.x; acc[(off)+7] += t.y; }

// ---------------------------------------------------------------------------
// Kernel 0: fp32 table -> fp16 table (one-time per call, 205 MB R + 98 MB W).
// ---------------------------------------------------------------------------
__global__ __launch_bounds__(256) void k_convert(const float* __restrict__ emb,
                                                 __half* __restrict__ embh) {
    const int nchunks = VROWS * (DD / 8);            // 6,400,128 chunks of 8
    const int idx = blockIdx.x * 256 + threadIdx.x;
    if (idx >= nchunks) return;
    const size_t base = (size_t)idx * 8;
    const float4 a = *(const float4*)(emb + base);
    const float4 b = *(const float4*)(emb + base + 4);
    float4 o;
    __half2* hp = (__half2*)&o;
    hp[0] = __float22half2_rn(make_float2(a.x, a.y));
    hp[1] = __float22half2_rn(make_float2(a.z, a.w));
    hp[2] = __float22half2_rn(make_float2(b.x, b.y));
    hp[3] = __float22half2_rn(make_float2(b.z, b.w));
    *(float4*)(embh + base) = o;
}

// ---------------------------------------------------------------------------
// Kernel 1: hidden[b,:] = (1/L) * sum_l embh[tok+1, :]  (fp16 rows, fp32 acc)
// Grid 256, 16 waves; wave sums 32 rows in EIGHT-row batches -> 16 x 1KB
// outstanding loads per wave (Little's law: match round-2 fp32 concurrency
// at half the bytes). VGPR ~90 under the (1024,4) cap of 128.
// ---------------------------------------------------------------------------
__global__ __launch_bounds__(1024, 4) void k_hidden(const int* __restrict__ tokens,
                                                    const __half* __restrict__ embh,
                                                    float* __restrict__ hidden) {
    __shared__ int   toks[LL];
    __shared__ float part[NW][DD];   // 64 KB

    const int b    = blockIdx.x;
    const int tid  = threadIdx.x;
    const int w    = tid >> 6;
    const int lane = tid & 63;
    const int o0   = lane * 8;
    const int o1   = 512 + lane * 8;

    if (tid < LL) toks[tid] = (tokens[b * LL + tid] + 1) * DD;
    __syncthreads();

    float acc[16];
    #pragma unroll
    for (int j = 0; j < 16; ++j) acc[j] = 0.f;

    #pragma unroll
    for (int i = 0; i < 32; i += 8) {
        float4 v[8][2];
        #pragma unroll
        for (int r = 0; r < 8; ++r) {
            const __half* rp = embh + toks[w * 32 + i + r];
            v[r][0] = *(const float4*)(rp + o0);
            v[r][1] = *(const float4*)(rp + o1);
        }
        #pragma unroll
        for (int r = 0; r < 8; ++r) {
            CVT8ADD(acc, 0, v[r][0]);
            CVT8ADD(acc, 8, v[r][1]);
        }
    }

    *(float4*)(&part[w][o0    ]) = make_float4(acc[0],  acc[1],  acc[2],  acc[3]);
    *(float4*)(&part[w][o0 + 4]) = make_float4(acc[4],  acc[5],  acc[6],  acc[7]);
    *(float4*)(&part[w][o1    ]) = make_float4(acc[8],  acc[9],  acc[10], acc[11]);
    *(float4*)(&part[w][o1 + 4]) = make_float4(acc[12], acc[13], acc[14], acc[15]);
    __syncthreads();

    float s = 0.f;
    #pragma unroll
    for (int j = 0; j < NW; ++j) s += part[j][tid];
    hidden[b * DD + tid] = s * (1.0f / (float)LL);
}

// ---------------------------------------------------------------------------
// Kernel 2: q[b,d] = sum_e W[d,e] * hidden[b,e]
// grid (16, 32), 256 threads; 8 docs/block halves W logical traffic (128 MB),
// 2 blocks/CU.
// ---------------------------------------------------------------------------
__global__ __launch_bounds__(256) void k_q(const float* __restrict__ hidden,
                                           const float* __restrict__ W,
                                           float* __restrict__ q) {
    __shared__ float hs[8][DD];   // 32 KB
    const int dt  = blockIdx.x;   // 0..15
    const int bt  = blockIdx.y;   // 0..31
    const int tid = threadIdx.x;

    #pragma unroll
    for (int j = 0; j < 8; ++j)
        #pragma unroll
        for (int k = 0; k < 4; ++k)
            hs[j][k * 256 + tid] = hidden[(bt * 8 + j) * DD + k * 256 + tid];
    __syncthreads();

    const int w = tid >> 6, lane = tid & 63;

    for (int i = 0; i < 16; ++i) {
        const int d = dt * 64 + w * 16 + i;
        float a[8];
        #pragma unroll
        for (int j = 0; j < 8; ++j) a[j] = 0.f;
        #pragma unroll
        for (int k = 0; k < 4; ++k) {
            const int off = k * 256 + lane * 4;
            const float4 wv = *(const float4*)(W + (size_t)d * DD + off);
            #pragma unroll
            for (int j = 0; j < 8; ++j) {
                const float4 h = *(const float4*)(&hs[j][off]);
                a[j] += wv.x * h.x + wv.y * h.y + wv.z * h.z + wv.w * h.w;
            }
        }
        #pragma unroll
        for (int m = 32; m; m >>= 1) {
            #pragma unroll
            for (int j = 0; j < 8; ++j) a[j] += __shfl_xor(a[j], m, 64);
        }
        if (lane == 0) {
            #pragma unroll
            for (int j = 0; j < 8; ++j) q[(bt * 8 + j) * DD + d] = a[j];
        }
    }
}

// ---------------------------------------------------------------------------
// Kernel 3: scores -> online softmax -> ct, fp16 rows / fp32 math.
// Grid 256, 16 waves x 32 rows, FOUR-row batches (8 x 1KB outstanding).
// Raw float4 loads stay in regs; converted at use (VALU is ~5% busy).
// One rescale per 4 rows. VGPR ~95 under the (1024,4) cap.
// ---------------------------------------------------------------------------
__global__ __launch_bounds__(1024, 4) void k_attn(const int* __restrict__ tokens,
                                                  const __half* __restrict__ embh,
                                                  const float* __restrict__ q,
                                                  float* __restrict__ out) {
    __shared__ int   toks[LL];
    __shared__ float ctp[NW][DD];   // 64 KB
    __shared__ float mw[NW], sw[NW];

    const int b    = blockIdx.x;
    const int tid  = threadIdx.x;
    const int w    = tid >> 6;
    const int lane = tid & 63;
    const int o0   = lane * 8;
    const int o1   = 512 + lane * 8;

    if (tid < LL) toks[tid] = (tokens[b * LL + tid] + 1) * DD;
    __syncthreads();

    float qa[16];
    {
        const float4 q00 = *(const float4*)(q + b * DD + o0);
        const float4 q01 = *(const float4*)(q + b * DD + o0 + 4);
        const float4 q10 = *(const float4*)(q + b * DD + o1);
        const float4 q11 = *(const float4*)(q + b * DD + o1 + 4);
        qa[0]=q00.x; qa[1]=q00.y; qa[2]=q00.z; qa[3]=q00.w;
        qa[4]=q01.x; qa[5]=q01.y; qa[6]=q01.z; qa[7]=q01.w;
        qa[8]=q10.x; qa[9]=q10.y; qa[10]=q10.z; qa[11]=q10.w;
        qa[12]=q11.x; qa[13]=q11.y; qa[14]=q11.z; qa[15]=q11.w;
    }

    float m = -1e30f, s = 0.f;
    float ct[16];
    #pragma unroll
    for (int j = 0; j < 16; ++j) ct[j] = 0.f;

    for (int i = 0; i < 32; i += 4) {
        float4 v[4][2];
        #pragma unroll
        for (int r = 0; r < 4; ++r) {
            const __half* rp = embh + toks[w * 32 + i + r];
            v[r][0] = *(const float4*)(rp + o0);
            v[r][1] = *(const float4*)(rp + o1);
        }

        float p[4];
        #pragma unroll
        for (int r = 0; r < 4; ++r) {
            float e[16];
            CVT8(e, 0, v[r][0]);
            CVT8(e, 8, v[r][1]);
            float pp = 0.f;
            #pragma unroll
            for (int j = 0; j < 16; ++j) pp += e[j] * qa[j];
            p[r] = pp;
        }
        #pragma unroll
        for (int mm = 32; mm; mm >>= 1) {
            p[0] += __shfl_xor(p[0], mm, 64);
            p[1] += __shfl_xor(p[1], mm, 64);
            p[2] += __shfl_xor(p[2], mm, 64);
            p[3] += __shfl_xor(p[3], mm, 64);
        }

        const float nm = fmaxf(fmaxf(m, fmaxf(p[0], p[1])), fmaxf(p[2], p[3]));
        const float f  = __expf(m - nm);
        const float w0 = __expf(p[0] - nm);
        const float w1 = __expf(p[1] - nm);
        const float w2 = __expf(p[2] - nm);
        const float w3 = __expf(p[3] - nm);
        s = s * f + w0 + w1 + w2 + w3;

        #pragma unroll
        for (int j = 0; j < 16; ++j) ct[j] *= f;
        {
            float e[16];
            CVT8(e, 0, v[0][0]); CVT8(e, 8, v[0][1]);
            #pragma unroll
            for (int j = 0; j < 16; ++j) ct[j] += w0 * e[j];
            CVT8(e, 0, v[1][0]); CVT8(e, 8, v[1][1]);
            #pragma unroll
            for (int j = 0; j < 16; ++j) ct[j] += w1 * e[j];
            CVT8(e, 0, v[2][0]); CVT8(e, 8, v[2][1]);
            #pragma unroll
            for (int j = 0; j < 16; ++j) ct[j] += w2 * e[j];
            CVT8(e, 0, v[3][0]); CVT8(e, 8, v[3][1]);
            #pragma unroll
            for (int j = 0; j < 16; ++j) ct[j] += w3 * e[j];
        }
        m = nm;
    }

    *(float4*)(&ctp[w][o0    ]) = make_float4(ct[0],  ct[1],  ct[2],  ct[3]);
    *(float4*)(&ctp[w][o0 + 4]) = make_float4(ct[4],  ct[5],  ct[6],  ct[7]);
    *(float4*)(&ctp[w][o1    ]) = make_float4(ct[8],  ct[9],  ct[10], ct[11]);
    *(float4*)(&ctp[w][o1 + 4]) = make_float4(ct[12], ct[13], ct[14], ct[15]);
    if (lane == 0) { mw[w] = m; sw[w] = s; }
    __syncthreads();

    float M = -1e30f;
    #pragma unroll
    for (int j = 0; j < NW; ++j) M = fmaxf(M, mw[j]);
    float denom = 0.f, sc[NW];
    #pragma unroll
    for (int j = 0; j < NW; ++j) { sc[j] = __expf(mw[j] - M); denom += sc[j] * sw[j]; }
    const float inv = 1.0f / denom;

    float acc = 0.f;
    #pragma unroll
    for (int j = 0; j < NW; ++j) acc += sc[j] * ctp[j][tid];
    out[b * DD + tid] = acc * inv;
}

// ---------------------------------------------------------------------------
extern "C" void kernel_launch(void* const* d_in, const int* in_sizes, int n_in,
                              void* d_out, int out_size, void* d_ws, size_t ws_size,
                              hipStream_t stream) {
    const int*   tokens = (const int*)d_in[0];
    // d_in[1] = max_len (scalar), fixed to LL
    const float* emb    = (const float*)d_in[2];
    const float* W      = (const float*)d_in[3];
    float*       out    = (float*)d_out;

    float*  hidden = (float*)d_ws;                       // 1 MB
    float*  q      = hidden + BB * DD;                   // 1 MB
    __half* embh   = (__half*)(q + BB * DD);             // ~98 MB

    const int nchunks = VROWS * (DD / 8);
    k_convert<<<(nchunks + 255) / 256, 256, 0, stream>>>(emb, embh);
    k_hidden<<<BB, 1024, 0, stream>>>(tokens, embh, hidden);
    dim3 g2(DD / 64, BB / 8);
    k_q<<<g2, 256, 0, stream>>>(hidden, W, q);
    k_attn<<<BB, 1024, 0, stream>>>(tokens, embh, q, out);
}